// Round 1
// baseline (173.119 us; speedup 1.0000x reference)
//
#include <hip/hip_runtime.h>
#include <math.h>

#define MM 16
#define CC 345
#define MC (MM*CC)   // 5520
#define KTOP 4

// One block per batch row b. 256 threads = 4 waves.
__global__ __launch_bounds__(256)
void ens_main(const float* __restrict__ y, const int* __restrict__ labels,
              float* __restrict__ out, float* __restrict__ partial, int B)
{
    const int b   = blockIdx.x;
    const int tid = threadIdx.x;

    __shared__ float sl[MC];          // logits tile (22080 B)
    __shared__ float sems[CC];        // ems_out
    __shared__ float s_truep[MM], s_epl[MM];
    __shared__ float s_w[MM], s_pw[MM];
    __shared__ float s_red[4];
    __shared__ float s_bmax;

    // ---- Phase 1: global -> LDS, vectorized float4 (tile is 16B aligned, 5520%4==0)
    {
        const float4* src = reinterpret_cast<const float4*>(y + (size_t)b * MC);
        float4* dst = reinterpret_cast<float4*>(sl);
        for (int i = tid; i < MC/4; i += 256) dst[i] = src[i];
    }
    __syncthreads();

    const int label = labels[b];

    // ---- Phase 2: per-m softmax stats, 16 lanes per m (16 groups x 16 lanes)
    {
        const int m = tid >> 4;
        const int l = tid & 15;
        const float* row = sl + m * CC;
        float mx = -INFINITY;
        for (int c = l; c < CC; c += 16) mx = fmaxf(mx, row[c]);
        #pragma unroll
        for (int off = 8; off; off >>= 1) mx = fmaxf(mx, __shfl_xor(mx, off, 16));
        float se = 0.f;
        for (int c = l; c < CC; c += 16) se += expf(row[c] - mx);
        #pragma unroll
        for (int off = 8; off; off >>= 1) se += __shfl_xor(se, off, 16);
        if (l == 0) {
            const float lt = row[label];
            s_truep[m] = expf(lt - mx) / se;          // probs[b,m,label]
            s_epl[m]   = -(lt - mx - logf(se));       // -log_softmax[b,m,label]
        }
    }
    __syncthreads();

    // ---- Phase 3: per-b M=16 vector math on thread 0 (tiny)
    if (tid == 0) {
        const size_t off_wm = (size_t)B * CC + 3;
        const size_t off_tc = off_wm + (size_t)B * MM;

        float tc[MM], wm[MM], xv[MM], tv[MM];
        // true_confs = softmax over M of true_p
        float mx = -INFINITY;
        for (int m = 0; m < MM; ++m) mx = fmaxf(mx, s_truep[m]);
        float se = 0.f;
        for (int m = 0; m < MM; ++m) { tc[m] = expf(s_truep[m] - mx); se += tc[m]; }
        for (int m = 0; m < MM; ++m) tc[m] /= se;
        // weighted_mat = l1_normalize(weights), weights = tc
        float s1 = 0.f;
        for (int m = 0; m < MM; ++m) s1 += fabsf(tc[m]);
        s1 = fmaxf(s1, 1e-12f);
        for (int m = 0; m < MM; ++m) wm[m] = tc[m] / s1;
        // top-4 (ties -> lowest index, per lax.top_k), scatter, l1-normalize
        float post[MM]; bool used[MM];
        for (int m = 0; m < MM; ++m) { post[m] = 0.f; used[m] = false; }
        float psum = 0.f;
        for (int k = 0; k < KTOP; ++k) {
            int bi = -1; float bv = -INFINITY;
            for (int m = 0; m < MM; ++m)
                if (!used[m] && tc[m] > bv) { bv = tc[m]; bi = m; }
            used[bi] = true; post[bi] = bv; psum += fabsf(bv);
        }
        psum = fmaxf(psum, 1e-12f);
        // x = softmax(wm), t = softmax(tc)
        float mw = -INFINITY, mt = -INFINITY;
        for (int m = 0; m < MM; ++m) { mw = fmaxf(mw, wm[m]); mt = fmaxf(mt, tc[m]); }
        float sw = 0.f, st = 0.f;
        for (int m = 0; m < MM; ++m) { xv[m] = expf(wm[m] - mw); sw += xv[m];
                                       tv[m] = expf(tc[m] - mt); st += tv[m]; }
        float child = 0.f, conf = 0.f;
        for (int m = 0; m < MM; ++m) {
            xv[m] /= sw; tv[m] /= st;
            child += s_epl[m] * xv[m];
            conf  += fmaxf(xv[m], 0.f) - xv[m] * tv[m] + log1pf(expf(-fabsf(xv[m])));
            s_w[m]  = wm[m];
            s_pw[m] = post[m] / psum;
            out[off_wm + (size_t)b * MM + m] = xv[m];  // wm_soft
            out[off_tc + (size_t)b * MM + m] = tc[m];  // true_confs
        }
        partial[(size_t)b * 3 + 0] = child;
        partial[(size_t)b * 3 + 1] = conf;
    }
    __syncthreads();

    // ---- Phase 4: ems_out / ems_out_post (16 FMAs per c per output)
    for (int c = tid; c < CC; c += 256) {
        float a = 0.f, ap = 0.f;
        #pragma unroll
        for (int m = 0; m < MM; ++m) {
            const float v = sl[m * CC + c];
            a  = fmaf(v, s_w[m],  a);
            ap = fmaf(v, s_pw[m], ap);
        }
        sems[c] = a;
        out[(size_t)b * CC + c] = ap;   // ems_out_post
    }
    __syncthreads();

    // ---- Phase 5: ensemble loss partial: -log_softmax(ems_out)[label]
    float mx = -INFINITY;
    for (int c = tid; c < CC; c += 256) mx = fmaxf(mx, sems[c]);
    #pragma unroll
    for (int off = 32; off; off >>= 1) mx = fmaxf(mx, __shfl_xor(mx, off));
    if ((tid & 63) == 0) s_red[tid >> 6] = mx;
    __syncthreads();
    if (tid == 0) s_bmax = fmaxf(fmaxf(s_red[0], s_red[1]), fmaxf(s_red[2], s_red[3]));
    __syncthreads();
    mx = s_bmax;
    float se = 0.f;
    for (int c = tid; c < CC; c += 256) se += expf(sems[c] - mx);
    #pragma unroll
    for (int off = 32; off; off >>= 1) se += __shfl_xor(se, off);
    if ((tid & 63) == 0) s_red[tid >> 6] = se;
    __syncthreads();
    if (tid == 0) {
        const float s = s_red[0] + s_red[1] + s_red[2] + s_red[3];
        partial[(size_t)b * 3 + 2] = -(sems[label] - mx - logf(s));
    }
}

// Deterministic fixed-order reduction of per-b partials -> the 3 scalar losses.
__global__ __launch_bounds__(256)
void ens_reduce(const float* __restrict__ partial, float* __restrict__ out, int B)
{
    const int tid = threadIdx.x;
    double c = 0.0, f = 0.0, e = 0.0;
    for (int i = tid; i < B; i += 256) {
        c += (double)partial[(size_t)i * 3 + 0];
        f += (double)partial[(size_t)i * 3 + 1];
        e += (double)partial[(size_t)i * 3 + 2];
    }
    #pragma unroll
    for (int off = 32; off; off >>= 1) {
        c += __shfl_xor(c, off);
        f += __shfl_xor(f, off);
        e += __shfl_xor(e, off);
    }
    __shared__ double rc[4], rf[4], re[4];
    if ((tid & 63) == 0) { rc[tid >> 6] = c; rf[tid >> 6] = f; re[tid >> 6] = e; }
    __syncthreads();
    if (tid == 0) {
        const double cs = rc[0] + rc[1] + rc[2] + rc[3];
        const double fs = rf[0] + rf[1] + rf[2] + rf[3];
        const double es = re[0] + re[1] + re[2] + re[3];
        const size_t base = (size_t)B * CC;
        out[base + 0] = (float)(cs / (double)((size_t)B * MM));  // child_loss
        out[base + 1] = (float)(fs / (double)((size_t)B * MM));  // confidence_loss
        out[base + 2] = (float)(es / (double)B);                 // ensemble_loss
    }
}

extern "C" void kernel_launch(void* const* d_in, const int* in_sizes, int n_in,
                              void* d_out, int out_size, void* d_ws, size_t ws_size,
                              hipStream_t stream)
{
    const float* y      = (const float*)d_in[0];
    const int*   labels = (const int*)d_in[1];
    const int    B      = in_sizes[1];      // 8192
    float* out     = (float*)d_out;
    float* partial = (float*)d_ws;          // B*3 floats = 96 KB

    ens_main<<<dim3(B), dim3(256), 0, stream>>>(y, labels, out, partial, B);
    ens_reduce<<<dim3(1), dim3(256), 0, stream>>>(partial, out, B);
}

// Round 5
// 80.023 us; speedup vs baseline: 2.1634x; 2.1634x over previous
//
#include <hip/hip_runtime.h>
#include <math.h>

#define MM 16
#define CC 345
#define MC (MM*CC)   // 5520
#define KTOP 4
#define GAP_THR 1e-5f

__device__ __forceinline__ float fexp(float x) { return __expf(x); }
__device__ __forceinline__ float flog(float x) { return __logf(x); }

// width-16 reductions over a 16-lane group
__device__ __forceinline__ float rmax16(float v) {
    #pragma unroll
    for (int off = 8; off; off >>= 1) v = fmaxf(v, __shfl_xor(v, off, 16));
    return v;
}
__device__ __forceinline__ float rmin16(float v) {
    #pragma unroll
    for (int off = 8; off; off >>= 1) v = fminf(v, __shfl_xor(v, off, 16));
    return v;
}
__device__ __forceinline__ float rsum16(float v) {
    #pragma unroll
    for (int off = 8; off; off >>= 1) v += __shfl_xor(v, off, 16);
    return v;
}

// One block per batch row b. 256 threads = 4 waves.
__global__ __launch_bounds__(256)
void ens_main(const float* __restrict__ y, const int* __restrict__ labels,
              float* __restrict__ out, float* __restrict__ partial, int B)
{
    const int b   = blockIdx.x;
    const int tid = threadIdx.x;

    __shared__ float sl[MC];          // logits tile (22080 B)
    __shared__ float sems[CC];        // ems_out
    __shared__ float s_truep[MM], s_epl[MM], s_mx[MM], s_tpp[MM];
    __shared__ float s_w[MM], s_pw[MM];
    __shared__ float s_red[4];
    __shared__ float s_bmax;
    __shared__ int   s_need;
    __shared__ unsigned s_selmask;

    // ---- Phase 1: global -> LDS, vectorized float4 (5520 % 4 == 0)
    {
        const float4* src = reinterpret_cast<const float4*>(y + (size_t)b * MC);
        float4* dst = reinterpret_cast<float4*>(sl);
        for (int i = tid; i < MC/4; i += 256) dst[i] = src[i];
    }
    __syncthreads();

    const int label = labels[b];

    // ---- Phase 2: per-m softmax stats (fast exp), 16 lanes per m.
    // mx is exp-free -> bit-identical to the round-1 (passing) arithmetic.
    {
        const int m = tid >> 4;
        const int l = tid & 15;
        const float* row = sl + m * CC;
        float mx = -INFINITY;
        for (int c = l; c < CC; c += 16) mx = fmaxf(mx, row[c]);
        mx = rmax16(mx);
        float se = 0.f;
        for (int c = l; c < CC; c += 16) se += fexp(row[c] - mx);
        se = rsum16(se);
        if (l == 0) {
            const float lt = row[label];
            s_mx[m]    = mx;                          // exact max, reused by 3b
            s_truep[m] = fexp(lt - mx) / se;          // fast probs[b,m,label]
            s_epl[m]   = -(lt - mx - flog(se));       // -log_softmax[b,m,label]
        }
    }
    __syncthreads();

    // ---- Phase 3a: fast per-b math + top-4 by rank, lanes 0..15 (one per m)
    float tc = 0.f, wm = 0.f;
    bool  sel = false;
    if (tid < MM) {
        const int l = tid;
        const float tp = s_truep[l];
        // true_confs = softmax over M of true_p
        const float mx = rmax16(tp);
        const float e  = fexp(tp - mx);
        tc = e / rsum16(e);
        // weighted_mat = l1_normalize(tc)
        const float s1 = fmaxf(rsum16(fabsf(tc)), 1e-12f);
        wm = tc / s1;
        // top-4 by rank (ties -> lowest index, matching lax.top_k)
        int rank = 0;
        #pragma unroll
        for (int j = 0; j < MM; ++j) {
            const float vj = __shfl(tc, j, 16);
            rank += (vj > tc) || (vj == tc && j < l);
        }
        sel = (rank < KTOP);
        // Boundary-gap guard: fast-exp perturbation on tc is bounded ~6e-8;
        // gap >= GAP_THR provably cannot flip membership vs libm arithmetic.
        const float val4 = rmin16(sel ? tc : INFINITY);    // smallest selected
        const float val5 = rmax16(sel ? -INFINITY : tc);   // largest unselected
        if (l == 0) s_need = (val4 - val5 < GAP_THR) ? 1 : 0;
    }
    __syncthreads();

    // ---- Phase 3b: guarded rows -> selection via BIT-EXACT round-1 chain:
    // libm expf, strided-16 sum + xor-tree (phase-2 pattern), then serial
    // m-ascending tc + 4x argmax on tid 0 (round-1 phase-3 verbatim).
    if (s_need) {
        {
            const int m = tid >> 4;
            const int l = tid & 15;
            const float* row = sl + m * CC;
            const float mx = s_mx[m];
            float se = 0.f;
            for (int c = l; c < CC; c += 16) se += expf(row[c] - mx);
            se = rsum16(se);
            if (l == 0) s_tpp[m] = expf(row[label] - mx) / se;
        }
        __syncthreads();
        if (tid == 0) {
            float tcp[MM];
            float mxx = -INFINITY;
            for (int m = 0; m < MM; ++m) mxx = fmaxf(mxx, s_tpp[m]);
            float ses = 0.f;
            for (int m = 0; m < MM; ++m) { tcp[m] = expf(s_tpp[m] - mxx); ses += tcp[m]; }
            for (int m = 0; m < MM; ++m) tcp[m] /= ses;
            bool used[MM];
            for (int m = 0; m < MM; ++m) used[m] = false;
            unsigned msk = 0;
            for (int k = 0; k < KTOP; ++k) {
                int bi = -1; float bv = -INFINITY;
                for (int m = 0; m < MM; ++m)
                    if (!used[m] && tcp[m] > bv) { bv = tcp[m]; bi = m; }
                used[bi] = true; msk |= (1u << bi);
            }
            s_selmask = msk;
        }
        __syncthreads();
    }

    // ---- Phase 3c: finish per-b math, lanes 0..15
    if (tid < MM) {
        const int l = tid;
        const size_t off_wm = (size_t)B * CC + 3;
        const size_t off_tc = off_wm + (size_t)B * MM;

        if (s_need) sel = ((s_selmask >> l) & 1u) != 0;

        const float post = sel ? tc : 0.f;
        const float psum = fmaxf(rsum16(fabsf(post)), 1e-12f);
        const float pw   = post / psum;
        // x = softmax(wm), t = softmax(tc) over M
        const float mw = rmax16(wm);
        const float ex = fexp(wm - mw);
        const float xv = ex / rsum16(ex);
        const float mt = rmax16(tc);
        const float et = fexp(tc - mt);
        const float tv = et / rsum16(et);
        // loss partials
        const float childp = s_epl[l] * xv;
        const float confp  = fmaxf(xv, 0.f) - xv * tv + flog(1.f + fexp(-fabsf(xv)));
        const float childs = rsum16(childp);
        const float confs  = rsum16(confp);
        if (l == 0) {
            partial[(size_t)b * 3 + 0] = childs;
            partial[(size_t)b * 3 + 1] = confs;
        }
        s_w[l]  = wm;
        s_pw[l] = pw;
        out[off_wm + (size_t)b * MM + l] = xv;  // wm_soft
        out[off_tc + (size_t)b * MM + l] = tc;  // true_confs
    }
    __syncthreads();

    // ---- Phase 4: ems_out / ems_out_post (16 FMAs per c per output)
    for (int c = tid; c < CC; c += 256) {
        float a = 0.f, ap = 0.f;
        #pragma unroll
        for (int m = 0; m < MM; ++m) {
            const float v = sl[m * CC + c];
            a  = fmaf(v, s_w[m],  a);
            ap = fmaf(v, s_pw[m], ap);
        }
        sems[c] = a;
        out[(size_t)b * CC + c] = ap;   // ems_out_post
    }
    __syncthreads();

    // ---- Phase 5: ensemble loss partial: -log_softmax(ems_out)[label]
    float mx = -INFINITY;
    for (int c = tid; c < CC; c += 256) mx = fmaxf(mx, sems[c]);
    #pragma unroll
    for (int off = 32; off; off >>= 1) mx = fmaxf(mx, __shfl_xor(mx, off));
    if ((tid & 63) == 0) s_red[tid >> 6] = mx;
    __syncthreads();
    if (tid == 0) s_bmax = fmaxf(fmaxf(s_red[0], s_red[1]), fmaxf(s_red[2], s_red[3]));
    __syncthreads();
    mx = s_bmax;
    float se = 0.f;
    for (int c = tid; c < CC; c += 256) se += fexp(sems[c] - mx);
    #pragma unroll
    for (int off = 32; off; off >>= 1) se += __shfl_xor(se, off);
    if ((tid & 63) == 0) s_red[tid >> 6] = se;
    __syncthreads();
    if (tid == 0) {
        const float s = s_red[0] + s_red[1] + s_red[2] + s_red[3];
        partial[(size_t)b * 3 + 2] = -(sems[label] - mx - flog(s));
    }
}

// Deterministic fixed-order reduction of per-b partials -> the 3 scalar losses.
__global__ __launch_bounds__(256)
void ens_reduce(const float* __restrict__ partial, float* __restrict__ out, int B)
{
    const int tid = threadIdx.x;
    double c = 0.0, f = 0.0, e = 0.0;
    for (int i = tid; i < B; i += 256) {
        c += (double)partial[(size_t)i * 3 + 0];
        f += (double)partial[(size_t)i * 3 + 1];
        e += (double)partial[(size_t)i * 3 + 2];
    }
    #pragma unroll
    for (int off = 32; off; off >>= 1) {
        c += __shfl_xor(c, off);
        f += __shfl_xor(f, off);
        e += __shfl_xor(e, off);
    }
    __shared__ double rc[4], rf[4], re[4];
    if ((tid & 63) == 0) { rc[tid >> 6] = c; rf[tid >> 6] = f; re[tid >> 6] = e; }
    __syncthreads();
    if (tid == 0) {
        const double cs = rc[0] + rc[1] + rc[2] + rc[3];
        const double fs = rf[0] + rf[1] + rf[2] + rf[3];
        const double es = re[0] + re[1] + re[2] + re[3];
        const size_t base = (size_t)B * CC;
        out[base + 0] = (float)(cs / (double)((size_t)B * MM));  // child_loss
        out[base + 1] = (float)(fs / (double)((size_t)B * MM));  // confidence_loss
        out[base + 2] = (float)(es / (double)B);                 // ensemble_loss
    }
}

extern "C" void kernel_launch(void* const* d_in, const int* in_sizes, int n_in,
                              void* d_out, int out_size, void* d_ws, size_t ws_size,
                              hipStream_t stream)
{
    const float* y      = (const float*)d_in[0];
    const int*   labels = (const int*)d_in[1];
    const int    B      = in_sizes[1];      // 8192
    float* out     = (float*)d_out;
    float* partial = (float*)d_ws;          // B*3 floats = 96 KB

    ens_main<<<dim3(B), dim3(256), 0, stream>>>(y, labels, out, partial, B);
    ens_reduce<<<dim3(1), dim3(256), 0, stream>>>(partial, out, B);
}